// Round 4
// baseline (529.122 us; speedup 1.0000x reference)
//
#include <hip/hip_runtime.h>

// LoraLinear NF4: out = x @ W_eff^T, W_eff = NF4[codes]*absmax + 2*(lora_B @ lora_A)
// M=8192 (4*2048), N=4096, K=4096. f16 MFMA GEMM, 256^2 8-phase template.
// R6: R3's proven sync skeleton + R4's intra-phase lgkm interleave + deeper
// stage freshness. Key lessons baked in:
//  - The per-tile vm wait MUST be VMC -> BAR at END of ph4 (R3 position):
//    vmcnt is per-wave, so a barrier must separate every wave's wait from any
//    wave's ds_read of the staged data. R5 waited at ph1 AFTER issuing reads
//    (race, two ways). Half-region consumption is wave-dependent, so the whole
//    next tile must be resident at its ph1 (R4's split waits: race).
//  - Stages: tile t ph1 -> {A1,B0,B1}(t+1) into BUF^1; ph4 -> A0(t+2) into BUF
//    (A0 can't stage earlier: ph3 still reads A0 rows 64..127). FIFO: after
//    each ph4-end vmcnt(2), exactly A0(t+2) in flight; newest demanded load
//    B1(t+1) is 3 phases (~2000cy) old >> 900cy HBM latency.
//  - Intra-phase counted lgkmcnt: reads in consumption order, MFMA clusters
//    start after 2-6 reads (LG(6/4/2/0)), rest drain under MFMA;
//    sched_barrier(0) after each wait (rule #18).
//  - Overwrite safety per region (>=1 closing barrier between last lgkm-drained
//    read and stage issue): B0 1 bar; A0 1 bar; A1/B1 >=2 bars.
// Tail: tile 62 stages tile 63 only, ph4-end vmcnt(0); tile 63 stages nothing.

typedef _Float16 half8 __attribute__((ext_vector_type(8)));
typedef float f32x4 __attribute__((ext_vector_type(4)));

#define M_DIM 8192
#define N_DIM 4096
#define K_DIM 4096
#define NT (K_DIM / 64)

__constant__ float NF4C[16] = {
    -1.0f, -0.6961928009986877f, -0.5250730514526367f, -0.39491748809814453f,
    -0.28444138169288635f, -0.18477343022823334f, -0.09105003625154495f, 0.0f,
    0.07958029955625534f, 0.16093020141124725f, 0.24611230194568634f, 0.33791524171829224f,
    0.44070982933044434f, 0.5626170039176941f, 0.7229568362236023f, 1.0f};

__device__ __forceinline__ void gl16(void* lds_p, const void* g) {
  __builtin_amdgcn_global_load_lds(
      (const __attribute__((address_space(1))) void*)g,
      (__attribute__((address_space(3))) void*)lds_p, 16, 0, 0);
}

// ---------------- prep_x: fp32 -> f16 cast of x ----------------
__global__ __launch_bounds__(256) void prep_x(const float4* __restrict__ x,
                                              half8* __restrict__ xh) {
  size_t i = (size_t)blockIdx.x * 256 + threadIdx.x;
  float4 a = x[2 * i];
  float4 b = x[2 * i + 1];
  half8 h;
  h[0] = (_Float16)a.x; h[1] = (_Float16)a.y; h[2] = (_Float16)a.z; h[3] = (_Float16)a.w;
  h[4] = (_Float16)b.x; h[5] = (_Float16)b.y; h[6] = (_Float16)b.z; h[7] = (_Float16)b.w;
  xh[i] = h;
}

// ---------------- prep_w: dequant NF4 + fold 2*B@A, write f16 ----------------
#define PWP 132
__global__ __launch_bounds__(256) void prep_w(const float* __restrict__ lora_A,
                                              const float* __restrict__ lora_B,
                                              const float* __restrict__ absmax,
                                              const int* __restrict__ codes,
                                              _Float16* __restrict__ Wc) {
  __shared__ float At[64 * PWP];
  __shared__ float Bt[64 * PWP];
  __shared__ float nf4s[16];
  const int tid = threadIdx.x;
  const int bxi = blockIdx.x & 31;
  const int byo = blockIdx.x >> 5;
  const int i0 = bxi * 128;
  const int o0 = byo * 128;
  if (tid < 16) nf4s[tid] = NF4C[tid];
  for (int idx = tid; idx < 8192; idx += 256) {
    int r = idx >> 7, ii = idx & 127;
    At[r * PWP + ii] = lora_A[(size_t)r * 4096 + i0 + ii];
  }
  for (int idx = tid; idx < 8192; idx += 256) {
    int oo = idx >> 6, r = idx & 63;
    Bt[r * PWP + oo] = lora_B[(size_t)(o0 + oo) * 64 + r];
  }
  __syncthreads();
  const int tx = tid & 15;
  const int ty = tid >> 4;
  float accw[8][8];
#pragma unroll
  for (int i = 0; i < 8; ++i)
#pragma unroll
    for (int j = 0; j < 8; ++j) accw[i][j] = 0.0f;
  for (int r = 0; r < 64; ++r) {
    float4 a0 = *(const float4*)&At[r * PWP + tx * 8];
    float4 a1 = *(const float4*)&At[r * PWP + tx * 8 + 4];
    float4 b0 = *(const float4*)&Bt[r * PWP + ty * 8];
    float4 b1 = *(const float4*)&Bt[r * PWP + ty * 8 + 4];
    float av[8] = {a0.x, a0.y, a0.z, a0.w, a1.x, a1.y, a1.z, a1.w};
    float bv[8] = {b0.x, b0.y, b0.z, b0.w, b1.x, b1.y, b1.z, b1.w};
#pragma unroll
    for (int i = 0; i < 8; ++i)
#pragma unroll
      for (int j = 0; j < 8; ++j) accw[i][j] += bv[i] * av[j];
  }
#pragma unroll
  for (int i = 0; i < 8; ++i) {
    const int o_g = o0 + ty * 8 + i;
    const int* crow = codes + (size_t)o_g * 4096 + i0 + tx * 8;
    int4 c0 = *(const int4*)crow;
    int4 c1 = *(const int4*)(crow + 4);
    const float am = absmax[o_g * 64 + (i0 >> 6) + (tx >> 3)];
    half8 h;
    h[0] = (_Float16)(nf4s[c0.x] * am + 2.0f * accw[i][0]);
    h[1] = (_Float16)(nf4s[c0.y] * am + 2.0f * accw[i][1]);
    h[2] = (_Float16)(nf4s[c0.z] * am + 2.0f * accw[i][2]);
    h[3] = (_Float16)(nf4s[c0.w] * am + 2.0f * accw[i][3]);
    h[4] = (_Float16)(nf4s[c1.x] * am + 2.0f * accw[i][4]);
    h[5] = (_Float16)(nf4s[c1.y] * am + 2.0f * accw[i][5]);
    h[6] = (_Float16)(nf4s[c1.z] * am + 2.0f * accw[i][6]);
    h[7] = (_Float16)(nf4s[c1.w] * am + 2.0f * accw[i][7]);
    *(half8*)(Wc + (size_t)o_g * 4096 + i0 + tx * 8) = h;
  }
}

// ---------------- gemm: C[M,N] = Xh[M,K] * Wc[N,K]^T ----------------
// LDS f16 offsets: region(buf,isB,half) = buf*32768 + isB*16384 + half*8192.
// Within region: row r (0..127), 16B chunk c (0..7); physical c = logical ^ (r&7).

#define BAR __builtin_amdgcn_s_barrier()
#define PRIO1 __builtin_amdgcn_s_setprio(1)
#define PRIO0 __builtin_amdgcn_s_setprio(0)
#define SB0 __builtin_amdgcn_sched_barrier(0)

#define VMC_(N) asm volatile("s_waitcnt vmcnt(" #N ")" ::: "memory")
#define VMC(N) VMC_(N)
#define LG_(N)                                              \
  do {                                                      \
    asm volatile("s_waitcnt lgkmcnt(" #N ")" ::: "memory"); \
    __builtin_amdgcn_sched_barrier(0);                      \
  } while (0)
#define LG(N) LG_(N)

__global__ __launch_bounds__(512, 2) void gemm(const _Float16* __restrict__ Xh,
                                               const _Float16* __restrict__ Wc,
                                               float* __restrict__ out) {
  __shared__ _Float16 lds[65536];  // 128 KiB
  const int tid = threadIdx.x;
  const int lane = tid & 63;
  const int w = tid >> 6;  // wave 0..7; 2M x 4N

  // T1: bijective XCD swizzle (512 wgs, 8 XCDs, 64 per XCD)
  const int swz = (blockIdx.x & 7) * 64 + (blockIdx.x >> 3);
  const int by = swz >> 4;  // 0..31 (M/256)
  const int bx = swz & 15;  // 0..15 (N/256)

  // fragment-read addressing (T2 swizzle on read side)
  const int m16 = lane & 15;
  const int quad = lane >> 4;
  const int csw = (quad ^ (m16 & 7)) * 8;
  const int aoff0 = m16 * 64 + csw;         // kk=0
  const int aoff1 = m16 * 64 + (csw ^ 32);  // kk=1
  const int ha = w >> 2;                    // wave's A half-region
  const int hboff = ((w & 3) >> 1) * 8192 + (w & 1) * 4096;

  // staging source (T2 inverse swizzle on global source; LDS dest linear)
  const int r0 = tid >> 3;
  const int lc = (tid & 7) ^ (r0 & 7);
  const _Float16* gAbase = Xh + (size_t)(by * 256 + r0) * K_DIM + lc * 8;
  const _Float16* gBbase = Wc + (size_t)(bx * 256 + r0) * K_DIM + lc * 8;

#define STAGE_A(H, BUF, T)                                                \
  do {                                                                    \
    _Float16* d_ = lds + (BUF) * 32768 + (H) * 8192 + w * 512;            \
    const _Float16* s_ = gAbase + (size_t)((H) * 128) * K_DIM + (T) * 64; \
    gl16(d_, s_);                                                         \
    gl16(d_ + 4096, s_ + (size_t)64 * K_DIM);                             \
  } while (0)
#define STAGE_B(H, BUF, T)                                                \
  do {                                                                    \
    _Float16* d_ = lds + (BUF) * 32768 + 16384 + (H) * 8192 + w * 512;    \
    const _Float16* s_ = gBbase + (size_t)((H) * 128) * K_DIM + (T) * 64; \
    gl16(d_, s_);                                                         \
    gl16(d_ + 4096, s_ + (size_t)64 * K_DIM);                             \
  } while (0)

  f32x4 acc[8][4];
#pragma unroll
  for (int m = 0; m < 8; ++m)
#pragma unroll
    for (int n = 0; n < 4; ++n) acc[m][n] = (f32x4){0.f, 0.f, 0.f, 0.f};

  half8 af[4][2];  // current A-half frags
  half8 bf[2][2];  // current B-half frags

#define RDA(FM, P)                                          \
  do {                                                      \
    af[FM][0] = *(const half8*)((P) + (FM)*1024 + aoff0);   \
    af[FM][1] = *(const half8*)((P) + (FM)*1024 + aoff1);   \
  } while (0)
#define RDB(FN, P)                                          \
  do {                                                      \
    bf[FN][0] = *(const half8*)((P) + (FN)*1024 + aoff0);   \
    bf[FN][1] = *(const half8*)((P) + (FN)*1024 + aoff1);   \
  } while (0)

  // row cluster: 4 MFMA using af[FM] x all bf
#define MFM(FM, MH, NH)                                                      \
  do {                                                                       \
    acc[(MH)*4 + (FM)][(NH)*2 + 0] = __builtin_amdgcn_mfma_f32_16x16x32_f16( \
        af[FM][0], bf[0][0], acc[(MH)*4 + (FM)][(NH)*2 + 0], 0, 0, 0);       \
    acc[(MH)*4 + (FM)][(NH)*2 + 0] = __builtin_amdgcn_mfma_f32_16x16x32_f16( \
        af[FM][1], bf[0][1], acc[(MH)*4 + (FM)][(NH)*2 + 0], 0, 0, 0);       \
    acc[(MH)*4 + (FM)][(NH)*2 + 1] = __builtin_amdgcn_mfma_f32_16x16x32_f16( \
        af[FM][0], bf[1][0], acc[(MH)*4 + (FM)][(NH)*2 + 1], 0, 0, 0);       \
    acc[(MH)*4 + (FM)][(NH)*2 + 1] = __builtin_amdgcn_mfma_f32_16x16x32_f16( \
        af[FM][1], bf[1][1], acc[(MH)*4 + (FM)][(NH)*2 + 1], 0, 0, 0);       \
  } while (0)

  // col cluster: 8 MFMA using bf[FN] x all af (af resident)
#define MFN(FN, MH, NH)                                                          \
  do {                                                                           \
    _Pragma("unroll") for (int fm_ = 0; fm_ < 4; ++fm_) {                        \
      acc[(MH)*4 + fm_][(NH)*2 + (FN)] = __builtin_amdgcn_mfma_f32_16x16x32_f16( \
          af[fm_][0], bf[FN][0], acc[(MH)*4 + fm_][(NH)*2 + (FN)], 0, 0, 0);     \
      acc[(MH)*4 + fm_][(NH)*2 + (FN)] = __builtin_amdgcn_mfma_f32_16x16x32_f16( \
          af[fm_][1], bf[FN][1], acc[(MH)*4 + fm_][(NH)*2 + (FN)], 0, 0, 0);     \
    }                                                                            \
  } while (0)

  // One K-tile (4 phases). Stages: ph1 -> {A1,B0,B1}(T+1); ph4 -> A0(T+2),
  // then VMC(VW); BAR publishes tile T+1 to all waves before its ph1 reads.
#define TILE(BUF, T, S1, S4, VW)                                        \
  do {                                                                  \
    const _Float16* rA = lds + (BUF)*32768 + ha * 8192;                 \
    const _Float16* rB = lds + (BUF)*32768 + 16384 + hboff;             \
    /* ---- ph1: quadrant (0,0) ---- */                                 \
    RDB(0, rB); RDB(1, rB); RDA(0, rA);                                 \
    SB0;                                                                \
    RDA(1, rA); RDA(2, rA); RDA(3, rA);                                 \
    if (S1) {                                                           \
      STAGE_A(1, (BUF) ^ 1, (T) + 1);                                   \
      STAGE_B(0, (BUF) ^ 1, (T) + 1);                                   \
      STAGE_B(1, (BUF) ^ 1, (T) + 1);                                   \
    }                                                                   \
    BAR;                                                                \
    PRIO1;                                                              \
    LG(6); MFM(0, 0, 0);                                                \
    LG(4); MFM(1, 0, 0);                                                \
    LG(2); MFM(2, 0, 0);                                                \
    LG(0); MFM(3, 0, 0);                                                \
    PRIO0;                                                              \
    BAR;                                                                \
    /* ---- ph2: (0,1) ---- */                                          \
    RDB(0, rB + 2048);                                                  \
    SB0;                                                                \
    RDB(1, rB + 2048);                                                  \
    BAR;                                                                \
    PRIO1;                                                              \
    LG(2); MFN(0, 0, 1);                                                \
    LG(0); MFN(1, 0, 1);                                                \
    PRIO0;                                                              \
    BAR;                                                                \
    /* ---- ph3: (1,1) ---- */                                          \
    RDA(0, rA + 4096);                                                  \
    SB0;                                                                \
    RDA(1, rA + 4096); RDA(2, rA + 4096); RDA(3, rA + 4096);            \
    BAR;                                                                \
    PRIO1;                                                              \
    LG(6); MFM(0, 1, 1);                                                \
    LG(4); MFM(1, 1, 1);                                                \
    LG(2); MFM(2, 1, 1);                                                \
    LG(0); MFM(3, 1, 1);                                                \
    PRIO0;                                                              \
    BAR;                                                                \
    /* ---- ph4: (1,0); re-reads B0; stage A0(T+2); publish T+1 ---- */ \
    RDB(0, rB);                                                         \
    SB0;                                                                \
    RDB(1, rB);                                                         \
    if (S4) STAGE_A(0, BUF, (T) + 2);                                   \
    BAR;                                                                \
    PRIO1;                                                              \
    LG(2); MFN(0, 1, 0);                                                \
    LG(0); MFN(1, 1, 0);                                                \
    PRIO0;                                                              \
    VMC(VW);                                                            \
    BAR;                                                                \
  } while (0)

  // prologue: tile0 {A0,A1,B0,B1} + tile1 A0 (10 loads); vmcnt(2) retires all
  // of tile0, leaves A0(1); BAR publishes across waves.
  STAGE_A(0, 0, 0);
  STAGE_A(1, 0, 0);
  STAGE_B(0, 0, 0);
  STAGE_B(1, 0, 0);
  STAGE_A(0, 1, 1);
  VMC(2);
  BAR;

  // steady state at each ph4-end vmcnt(2): only A0(t+2) stays in flight;
  // newest demanded load B1(t+1) was staged at tile t ph1 (3 phases old).
  for (int t2 = 0; t2 < NT - 2; t2 += 2) {
    TILE(0, t2, 1, 1, 2);
    TILE(1, t2 + 1, 1, 1, 2);
  }
  // tile NT-2: stages tile NT-1's {A1,B0,B1} only; drain them (vmcnt 0)
  TILE(0, NT - 2, 1, 0, 0);
  // tile NT-1: stages nothing
  TILE(1, NT - 1, 0, 0, 0);

  // epilogue: C/D layout col=lane&15, row=quad*4+reg
  const size_t rowbase = (size_t)by * 256 + ha * 128 + quad * 4;
  const int colbase = bx * 256 + (w & 3) * 64 + m16;
#pragma unroll
  for (int m = 0; m < 8; ++m) {
#pragma unroll
    for (int r = 0; r < 4; ++r) {
      float* po = out + (rowbase + m * 16 + r) * N_DIM + colbase;
      po[0]  = acc[m][0][r];
      po[16] = acc[m][1][r];
      po[32] = acc[m][2][r];
      po[48] = acc[m][3][r];
    }
  }
}

extern "C" void kernel_launch(void* const* d_in, const int* in_sizes, int n_in,
                              void* d_out, int out_size, void* d_ws, size_t ws_size,
                              hipStream_t stream) {
  const float* x      = (const float*)d_in[0];
  const float* lora_A = (const float*)d_in[1];
  const float* lora_B = (const float*)d_in[2];
  const float* absmax = (const float*)d_in[3];
  const int*   codes  = (const int*)d_in[4];
  float* out = (float*)d_out;

  _Float16* Xh = (_Float16*)d_ws;                 // 8192*4096 f16 = 64 MiB
  _Float16* Wc = Xh + (size_t)M_DIM * K_DIM;      // 4096*4096 f16 = 32 MiB

  hipLaunchKernelGGL(prep_x, dim3((M_DIM * K_DIM) / (8 * 256)), dim3(256), 0, stream,
                     (const float4*)x, (half8*)Xh);
  hipLaunchKernelGGL(prep_w, dim3((N_DIM / 128) * (K_DIM / 128)), dim3(256), 0, stream,
                     lora_A, lora_B, absmax, codes, Wc);
  hipLaunchKernelGGL(gemm, dim3((M_DIM / 256) * (N_DIM / 256)), dim3(512), 0, stream,
                     Xh, Wc, out);
}